// Round 3
// baseline (1272.537 us; speedup 1.0000x reference)
//
#include <hip/hip_runtime.h>

// Problem constants (from reference)
#define NUu 200000
#define NIi 100000
#define EE  600000
// D = H = 128

typedef short short8 __attribute__((ext_vector_type(8)));
typedef float floatx4 __attribute__((ext_vector_type(4)));

// float -> bf16 bits, round-to-nearest-even
__device__ __forceinline__ unsigned short f2bf(float f) {
  union { float f; unsigned int u; } v; v.f = f;
  unsigned int r = v.u + 0x7FFFu + ((v.u >> 16) & 1u);
  return (unsigned short)(r >> 16);
}

// ---------------------------------------------------------------------------
// K0a: fused weights  W1 = Wl @ W2nd,  W2 = Wr @ W2nd  -> bf16, packed in the
// MFMA B-fragment layout:  elem index = ((n_tile*8 + k_step)*64 + quad*16 + n_lo)*8 + j
// where k_global = k_step*32 + quad*8 + j, n = n_tile*16 + n_lo.
// ---------------------------------------------------------------------------
__global__ __launch_bounds__(128) void fuse_weights(
    const float* __restrict__ Wl_iu, const float* __restrict__ Wr_iu,
    const float* __restrict__ Wl_ui, const float* __restrict__ Wr_ui,
    const float* __restrict__ W_user, const float* __restrict__ W_item,
    unsigned short* __restrict__ Wp_user, unsigned short* __restrict__ Wp_item)
{
  int d = blockIdx.x;        // 0..127 (row of first factor)
  int m = blockIdx.y;        // which matrix
  int h = threadIdx.x;       // 0..127 (output col)
  const float* A; const float* W; unsigned short* dst; int koff;
  switch (m) {
    case 0:  A = Wl_iu; W = W_user; dst = Wp_user; koff = 0;   break;
    case 1:  A = Wr_iu; W = W_user; dst = Wp_user; koff = 128; break;
    case 2:  A = Wl_ui; W = W_item; dst = Wp_item; koff = 0;   break;
    default: A = Wr_ui; W = W_item; dst = Wp_item; koff = 128; break;
  }
  float acc = 0.f;
  for (int k = 0; k < 128; ++k) acc += A[d * 128 + k] * W[k * 128 + h];
  int kg = koff + d;
  int ks = kg >> 5, quad = (kg >> 3) & 3, j = kg & 7;
  int nt = h >> 4, nlo = h & 15;
  int idx = ((nt * 8 + ks) * 64 + quad * 16 + nlo) * 8 + j;
  dst[idx] = f2bf(acc);
}

// K0b: fused bias = bl @ W2nd + b2nd   (fp32). grid 2, block 128.
__global__ __launch_bounds__(128) void fuse_bias(
    const float* __restrict__ bl_iu, const float* __restrict__ b_user, const float* __restrict__ Wu,
    const float* __restrict__ bl_ui, const float* __restrict__ b_item, const float* __restrict__ Wi,
    float* __restrict__ bias_user, float* __restrict__ bias_item)
{
  int h = threadIdx.x;
  const float* bl = blockIdx.x ? bl_ui : bl_iu;
  const float* b2 = blockIdx.x ? b_item : b_user;
  const float* W  = blockIdx.x ? Wi : Wu;
  float* o        = blockIdx.x ? bias_item : bias_user;
  float acc = b2[h];
  for (int k = 0; k < 128; ++k) acc += bl[k] * W[k * 128 + h];
  o[h] = acc;
}

// ---------------------------------------------------------------------------
// CSR construction: hist -> scan1 -> scan2 -> scan3 -> fill
// ---------------------------------------------------------------------------
__global__ __launch_bounds__(256) void hist(const int* __restrict__ edst,
                                            int* __restrict__ cnt, int E)
{
  int e = blockIdx.x * 256 + threadIdx.x;
  if (e < E) atomicAdd(&cnt[edst[e]], 1);
}

__global__ __launch_bounds__(256) void scan1(const int* __restrict__ cnt,
                                             int* __restrict__ blksum, int N)
{
  __shared__ int s[256];
  int b = blockIdx.x, t = threadIdx.x;
  int base = b * 1024 + t * 4;
  int v = 0;
  #pragma unroll
  for (int j = 0; j < 4; ++j) { int i = base + j; if (i < N) v += cnt[i]; }
  s[t] = v; __syncthreads();
  for (int off = 128; off > 0; off >>= 1) {
    if (t < off) s[t] += s[t + off];
    __syncthreads();
  }
  if (t == 0) blksum[b] = s[0];
}

__global__ __launch_bounds__(256) void scan2(const int* __restrict__ blksum,
                                             int* __restrict__ blkoff, int nblk)
{
  __shared__ int s[256];
  int t = threadIdx.x;
  int v = t < nblk ? blksum[t] : 0;
  s[t] = v; __syncthreads();
  for (int off = 1; off < 256; off <<= 1) {
    int tmp = t >= off ? s[t - off] : 0;
    __syncthreads();
    s[t] += tmp;
    __syncthreads();
  }
  if (t < nblk) blkoff[t] = s[t] - v;
}

__global__ __launch_bounds__(256) void scan3(const int* __restrict__ cnt,
                                             const int* __restrict__ blkoff,
                                             int* __restrict__ rowp,
                                             int* __restrict__ fillp, int N)
{
  __shared__ int s[256];
  int b = blockIdx.x, t = threadIdx.x;
  int base = b * 1024 + t * 4;
  int v[4]; int sum = 0;
  #pragma unroll
  for (int j = 0; j < 4; ++j) { int i = base + j; v[j] = (i < N) ? cnt[i] : 0; sum += v[j]; }
  s[t] = sum; __syncthreads();
  for (int off = 1; off < 256; off <<= 1) {
    int tmp = t >= off ? s[t - off] : 0;
    __syncthreads();
    s[t] += tmp;
    __syncthreads();
  }
  int ex = s[t] - sum + blkoff[b];
  #pragma unroll
  for (int j = 0; j < 4; ++j) {
    int i = base + j;
    if (i < N) { rowp[i] = ex; fillp[i] = ex; ex += v[j]; }
  }
}

__global__ __launch_bounds__(256) void fill(const int* __restrict__ esrc,
                                            const int* __restrict__ edst,
                                            int* __restrict__ fillp,
                                            int* __restrict__ srcs, int E)
{
  int e = blockIdx.x * 256 + threadIdx.x;
  if (e < E) {
    int d = edst[e];
    int p = atomicAdd(&fillp[d], 1);
    srcs[p] = esrc[e];
  }
}

// ---------------------------------------------------------------------------
// K3: fused node kernel, edge-parallel aggregation:
//   out = relu( mean_{s in N(node)} x_src[s] @ W1 + x_own @ W2 + bias )
// Block = 64 nodes. Phase 1: edge-parallel LDS fp32 accumulation (16 groups
// of 16 lanes, one edge per group-step, ds_add_f32, accum stride 132 floats
// to spread banks). Phase 2: scale by 1/deg, bf16-pack into MFMA A-frag
// layout ALIASED over the accumulator (2 rounds, read->bar->write; regions
// verified disjoint across rounds). Phase 3: MFMA + bias + relu epilogue.
// mfma_f32_16x16x32_bf16 C/D: col=lane&15, row=(lane>>4)*4+reg   (m89/m91)
// ---------------------------------------------------------------------------
__global__ __launch_bounds__(256, 4) void fused_gemm(
    const float* __restrict__ xown, const float* __restrict__ xsrc,
    const int* __restrict__ rowp, const int* __restrict__ srcs,
    const unsigned short* __restrict__ Wp, const float* __restrict__ bias,
    float* __restrict__ outbase, int nvalid, int etotal)
{
  __shared__ __align__(16) float accf[8704];   // 34 KB: fp32 accum, then packed A
  __shared__ int rb[65];                       // block row pointers
  int t = threadIdx.x;
  int node0 = blockIdx.x * 64;

  // row-pointer table (clamped at etotal for nodes past the end)
  if (t < 65) {
    int node = node0 + t;
    rb[t] = node < nvalid ? rowp[node] : etotal;
  }
  // zero accumulator (2112 float4 = 8448 floats)
  float4 z4 = make_float4(0.f, 0.f, 0.f, 0.f);
  #pragma unroll
  for (int i = 0; i < 9; ++i) {
    int idx = t + i * 256;
    if (idx < 2112) ((float4*)accf)[idx] = z4;
  }
  __syncthreads();

  // ---- phase 1: edge-parallel accumulate ----
  int grp = t >> 4, lj = t & 15;
  int rs0 = rb[0], rs1 = rb[64];
  for (int p = rs0 + grp; p < rs1; p += 16) {
    int sidx = srcs[p];
    // largest m in [0,63] with rb[m] <= p  (rb nondecreasing, p < rb[64])
    int m = 0;
    #pragma unroll
    for (int stp = 32; stp >= 1; stp >>= 1) {
      int cand = m + stp;
      if (rb[cand] <= p) m = cand;   // cand <= 63 by construction
    }
    const float4* row = (const float4*)(xsrc + (size_t)sidx * 128);
    float4 v0 = row[lj];        // k = lj*4 .. +3
    float4 v1 = row[lj + 16];   // k = 64 + lj*4 .. +3
    float* a = accf + m * 132 + lj * 4;
    atomicAdd(a + 0, v0.x);
    atomicAdd(a + 1, v0.y);
    atomicAdd(a + 2, v0.z);
    atomicAdd(a + 3, v0.w);
    atomicAdd(a + 64, v1.x);
    atomicAdd(a + 65, v1.y);
    atomicAdd(a + 66, v1.z);
    atomicAdd(a + 67, v1.w);
  }
  __syncthreads();

  // ---- phase 2: scale + bf16 pack into A-frag layout (aliased, 2 rounds) --
  // thread's oct is invariant across i (256 % 32 == 0): all-agg or all-own
  uint4* ldsA4 = (uint4*)accf;
  int oct = t & 31;
  bool isagg = oct < 16;
  int k0 = isagg ? oct * 8 : (oct - 16) * 8;
  int ks = oct & 15 ? (oct & 15) >> 2 : 0;   // placeholder, recomputed below
  ks = (isagg ? oct : (oct - 16)) >> 1;      // not used; real ks below
  #pragma unroll
  for (int r = 0; r < 2; ++r) {
    float vals[4][8];
    #pragma unroll
    for (int ii = 0; ii < 4; ++ii) {
      int i = r * 4 + ii;
      int m = (t + i * 256) >> 5;
      int node = node0 + m;
      if (isagg) {
        int deg = rb[m + 1] - rb[m];
        float sc = deg > 0 ? 1.0f / (float)deg : 0.f;
        float4 lo4 = *(const float4*)(accf + m * 132 + k0);
        float4 hi4 = *(const float4*)(accf + m * 132 + k0 + 4);
        vals[ii][0] = lo4.x * sc; vals[ii][1] = lo4.y * sc;
        vals[ii][2] = lo4.z * sc; vals[ii][3] = lo4.w * sc;
        vals[ii][4] = hi4.x * sc; vals[ii][5] = hi4.y * sc;
        vals[ii][6] = hi4.z * sc; vals[ii][7] = hi4.w * sc;
      } else if (node < nvalid) {
        const float4* p4 = (const float4*)(xown + (size_t)node * 128 + k0);
        float4 lo4 = p4[0], hi4 = p4[1];
        vals[ii][0] = lo4.x; vals[ii][1] = lo4.y;
        vals[ii][2] = lo4.z; vals[ii][3] = lo4.w;
        vals[ii][4] = hi4.x; vals[ii][5] = hi4.y;
        vals[ii][6] = hi4.z; vals[ii][7] = hi4.w;
      } else {
        #pragma unroll
        for (int j2 = 0; j2 < 8; ++j2) vals[ii][j2] = 0.f;
      }
    }
    __syncthreads();   // all round-r reads done before overwriting
    #pragma unroll
    for (int ii = 0; ii < 4; ++ii) {
      int i = r * 4 + ii;
      int m = (t + i * 256) >> 5;
      uint4 p;
      p.x = (unsigned)f2bf(vals[ii][0]) | ((unsigned)f2bf(vals[ii][1]) << 16);
      p.y = (unsigned)f2bf(vals[ii][2]) | ((unsigned)f2bf(vals[ii][3]) << 16);
      p.z = (unsigned)f2bf(vals[ii][4]) | ((unsigned)f2bf(vals[ii][5]) << 16);
      p.w = (unsigned)f2bf(vals[ii][6]) | ((unsigned)f2bf(vals[ii][7]) << 16);
      int kss = oct >> 2, quad = oct & 3;          // k_global = oct*8
      int mt = m >> 4, mlo = m & 15;
      ldsA4[(mt * 8 + kss) * 64 + quad * 16 + mlo] = p;
    }
    __syncthreads();
  }

  // ---- phase 3: MFMA, wave = m-tile (16 nodes), 8 n-tiles, K=256 ----
  int wave = t >> 6, lane = t & 63;
  floatx4 acc[8];
  #pragma unroll
  for (int i = 0; i < 8; ++i) acc[i] = (floatx4){0.f, 0.f, 0.f, 0.f};
  const short8* A = (const short8*)ldsA4;
  const short8* B = (const short8*)Wp;
  #pragma unroll
  for (int kk = 0; kk < 8; ++kk) {
    short8 af = A[(wave * 8 + kk) * 64 + lane];
    #pragma unroll
    for (int nt = 0; nt < 8; ++nt) {
      short8 bf = B[(nt * 8 + kk) * 64 + lane];
      acc[nt] = __builtin_amdgcn_mfma_f32_16x16x32_bf16(af, bf, acc[nt], 0, 0, 0);
    }
  }

  // ---- epilogue: bias + relu ----
  int col = lane & 15, qrow = (lane >> 4) * 4;
  #pragma unroll
  for (int nt = 0; nt < 8; ++nt) {
    int n = nt * 16 + col;
    float bv = bias[n];
    #pragma unroll
    for (int r2 = 0; r2 < 4; ++r2) {
      int node = node0 + wave * 16 + qrow + r2;
      if (node < nvalid) {
        float v = acc[nt][r2] + bv;
        outbase[(size_t)node * 128 + n] = v > 0.f ? v : 0.f;
      }
    }
  }
}

// ---------------------------------------------------------------------------
// Workspace layout (bytes), total ~8.54 MB (cnt_* zeroed each call):
//   cnt_user @0 800000 | cnt_item @800000 400000 | row_user @1200000 800000
//   row_item @2000000 400000 | fill_user @2400000 800000 | fill_item @3200000 400000
//   srcs_user @3600000 2400000 | srcs_item @6000000 2400000
//   blks_user @8400000 1024 | blks_item @8401024 1024
//   boff_user @8402048 1024 | boff_item @8403072 1024
//   Wp_user @8404224 65536 | Wp_item @8469760 65536
//   bias_user @8535296 512 | bias_item @8535808 512
// ---------------------------------------------------------------------------
extern "C" void kernel_launch(void* const* d_in, const int* in_sizes, int n_in,
                              void* d_out, int out_size, void* d_ws, size_t ws_size,
                              hipStream_t stream)
{
  const float* x_user = (const float*)d_in[0];
  const float* x_item = (const float*)d_in[1];
  const int* esrc_ui  = (const int*)d_in[2];
  const int* edst_ui  = (const int*)d_in[3];
  const int* esrc_iu  = (const int*)d_in[4];
  const int* edst_iu  = (const int*)d_in[5];
  const float* Wl_ui  = (const float*)d_in[6];
  const float* bl_ui  = (const float*)d_in[7];
  const float* Wr_ui  = (const float*)d_in[8];
  const float* Wl_iu  = (const float*)d_in[9];
  const float* bl_iu  = (const float*)d_in[10];
  const float* Wr_iu  = (const float*)d_in[11];
  const float* W_user = (const float*)d_in[12];
  const float* b_user = (const float*)d_in[13];
  const float* W_item = (const float*)d_in[14];
  const float* b_item = (const float*)d_in[15];
  float* out = (float*)d_out;

  char* ws = (char*)d_ws;
  int* cnt_user  = (int*)(ws + 0);
  int* cnt_item  = (int*)(ws + 800000);
  int* row_user  = (int*)(ws + 1200000);
  int* row_item  = (int*)(ws + 2000000);
  int* fill_user = (int*)(ws + 2400000);
  int* fill_item = (int*)(ws + 3200000);
  int* srcs_user = (int*)(ws + 3600000);
  int* srcs_item = (int*)(ws + 6000000);
  int* blks_user = (int*)(ws + 8400000);
  int* blks_item = (int*)(ws + 8401024);
  int* boff_user = (int*)(ws + 8402048);
  int* boff_item = (int*)(ws + 8403072);
  unsigned short* Wp_user = (unsigned short*)(ws + 8404224);
  unsigned short* Wp_item = (unsigned short*)(ws + 8469760);
  float* bias_user = (float*)(ws + 8535296);
  float* bias_item = (float*)(ws + 8535808);

  // zero only the histograms (1.2 MB)
  hipMemsetAsync(d_ws, 0, 1200000, stream);

  fuse_weights<<<dim3(128, 4), 128, 0, stream>>>(Wl_iu, Wr_iu, Wl_ui, Wr_ui,
                                                 W_user, W_item, Wp_user, Wp_item);
  fuse_bias<<<2, 128, 0, stream>>>(bl_iu, b_user, W_user, bl_ui, b_item, W_item,
                                   bias_user, bias_item);

  const int EB = (EE + 255) / 256;            // 2344
  const int NBU = (NUu + 1023) / 1024;        // 196
  const int NBI = (NIi + 1023) / 1024;        // 98

  hist<<<EB, 256, 0, stream>>>(edst_iu, cnt_user, EE);
  hist<<<EB, 256, 0, stream>>>(edst_ui, cnt_item, EE);

  scan1<<<NBU, 256, 0, stream>>>(cnt_user, blks_user, NUu);
  scan1<<<NBI, 256, 0, stream>>>(cnt_item, blks_item, NIi);
  scan2<<<1, 256, 0, stream>>>(blks_user, boff_user, NBU);
  scan2<<<1, 256, 0, stream>>>(blks_item, boff_item, NBI);
  scan3<<<NBU, 256, 0, stream>>>(cnt_user, boff_user, row_user, fill_user, NUu);
  scan3<<<NBI, 256, 0, stream>>>(cnt_item, boff_item, row_item, fill_item, NIi);

  fill<<<EB, 256, 0, stream>>>(esrc_iu, edst_iu, fill_user, srcs_user, EE);
  fill<<<EB, 256, 0, stream>>>(esrc_ui, edst_ui, fill_item, srcs_item, EE);

  fused_gemm<<<(NUu + 63) / 64, 256, 0, stream>>>(x_user, x_item, row_user,
                                                  srcs_user, Wp_user, bias_user,
                                                  out, NUu, EE);
  fused_gemm<<<(NIi + 63) / 64, 256, 0, stream>>>(x_item, x_user, row_item,
                                                  srcs_item, Wp_item, bias_item,
                                                  out + (size_t)NUu * 128, NIi, EE);
}

// Round 4
// 602.357 us; speedup vs baseline: 2.1126x; 2.1126x over previous
//
#include <hip/hip_runtime.h>

// Problem constants (from reference)
#define NUu 200000
#define NIi 100000
#define EE  600000
// D = H = 128

#define SCAP 1024   // LDS src-index window capacity (block edge windows are ~192/~384 avg)

typedef short short8 __attribute__((ext_vector_type(8)));
typedef float floatx4 __attribute__((ext_vector_type(4)));

// float -> bf16 bits, round-to-nearest-even
__device__ __forceinline__ unsigned short f2bf(float f) {
  union { float f; unsigned int u; } v; v.f = f;
  unsigned int r = v.u + 0x7FFFu + ((v.u >> 16) & 1u);
  return (unsigned short)(r >> 16);
}

// ---------------------------------------------------------------------------
// K0a: fused weights  W1 = Wl @ W2nd,  W2 = Wr @ W2nd  -> bf16, packed in the
// MFMA B-fragment layout:  elem index = ((n_tile*8 + k_step)*64 + quad*16 + n_lo)*8 + j
// where k_global = k_step*32 + quad*8 + j, n = n_tile*16 + n_lo.
// ---------------------------------------------------------------------------
__global__ __launch_bounds__(128) void fuse_weights(
    const float* __restrict__ Wl_iu, const float* __restrict__ Wr_iu,
    const float* __restrict__ Wl_ui, const float* __restrict__ Wr_ui,
    const float* __restrict__ W_user, const float* __restrict__ W_item,
    unsigned short* __restrict__ Wp_user, unsigned short* __restrict__ Wp_item)
{
  int d = blockIdx.x;        // 0..127 (row of first factor)
  int m = blockIdx.y;        // which matrix
  int h = threadIdx.x;       // 0..127 (output col)
  const float* A; const float* W; unsigned short* dst; int koff;
  switch (m) {
    case 0:  A = Wl_iu; W = W_user; dst = Wp_user; koff = 0;   break;
    case 1:  A = Wr_iu; W = W_user; dst = Wp_user; koff = 128; break;
    case 2:  A = Wl_ui; W = W_item; dst = Wp_item; koff = 0;   break;
    default: A = Wr_ui; W = W_item; dst = Wp_item; koff = 128; break;
  }
  float acc = 0.f;
  for (int k = 0; k < 128; ++k) acc += A[d * 128 + k] * W[k * 128 + h];
  int kg = koff + d;
  int ks = kg >> 5, quad = (kg >> 3) & 3, j = kg & 7;
  int nt = h >> 4, nlo = h & 15;
  int idx = ((nt * 8 + ks) * 64 + quad * 16 + nlo) * 8 + j;
  dst[idx] = f2bf(acc);
}

// K0b: fused bias = bl @ W2nd + b2nd   (fp32). grid 2, block 128.
__global__ __launch_bounds__(128) void fuse_bias(
    const float* __restrict__ bl_iu, const float* __restrict__ b_user, const float* __restrict__ Wu,
    const float* __restrict__ bl_ui, const float* __restrict__ b_item, const float* __restrict__ Wi,
    float* __restrict__ bias_user, float* __restrict__ bias_item)
{
  int h = threadIdx.x;
  const float* bl = blockIdx.x ? bl_ui : bl_iu;
  const float* b2 = blockIdx.x ? b_item : b_user;
  const float* W  = blockIdx.x ? Wi : Wu;
  float* o        = blockIdx.x ? bias_item : bias_user;
  float acc = b2[h];
  for (int k = 0; k < 128; ++k) acc += bl[k] * W[k * 128 + h];
  o[h] = acc;
}

// ---------------------------------------------------------------------------
// CSR construction: hist -> scan1 -> scan2 -> scan3 -> fill
// ---------------------------------------------------------------------------
__global__ __launch_bounds__(256) void hist(const int* __restrict__ edst,
                                            int* __restrict__ cnt, int E)
{
  int e = blockIdx.x * 256 + threadIdx.x;
  if (e < E) atomicAdd(&cnt[edst[e]], 1);
}

__global__ __launch_bounds__(256) void scan1(const int* __restrict__ cnt,
                                             int* __restrict__ blksum, int N)
{
  __shared__ int s[256];
  int b = blockIdx.x, t = threadIdx.x;
  int base = b * 1024 + t * 4;
  int v = 0;
  #pragma unroll
  for (int j = 0; j < 4; ++j) { int i = base + j; if (i < N) v += cnt[i]; }
  s[t] = v; __syncthreads();
  for (int off = 128; off > 0; off >>= 1) {
    if (t < off) s[t] += s[t + off];
    __syncthreads();
  }
  if (t == 0) blksum[b] = s[0];
}

__global__ __launch_bounds__(256) void scan2(const int* __restrict__ blksum,
                                             int* __restrict__ blkoff, int nblk)
{
  __shared__ int s[256];
  int t = threadIdx.x;
  int v = t < nblk ? blksum[t] : 0;
  s[t] = v; __syncthreads();
  for (int off = 1; off < 256; off <<= 1) {
    int tmp = t >= off ? s[t - off] : 0;
    __syncthreads();
    s[t] += tmp;
    __syncthreads();
  }
  if (t < nblk) blkoff[t] = s[t] - v;
}

__global__ __launch_bounds__(256) void scan3(const int* __restrict__ cnt,
                                             const int* __restrict__ blkoff,
                                             int* __restrict__ rowp,
                                             int* __restrict__ fillp, int N)
{
  __shared__ int s[256];
  int b = blockIdx.x, t = threadIdx.x;
  int base = b * 1024 + t * 4;
  int v[4]; int sum = 0;
  #pragma unroll
  for (int j = 0; j < 4; ++j) { int i = base + j; v[j] = (i < N) ? cnt[i] : 0; sum += v[j]; }
  s[t] = sum; __syncthreads();
  for (int off = 1; off < 256; off <<= 1) {
    int tmp = t >= off ? s[t - off] : 0;
    __syncthreads();
    s[t] += tmp;
    __syncthreads();
  }
  int ex = s[t] - sum + blkoff[b];
  #pragma unroll
  for (int j = 0; j < 4; ++j) {
    int i = base + j;
    if (i < N) { rowp[i] = ex; fillp[i] = ex; ex += v[j]; }
  }
}

__global__ __launch_bounds__(256) void fill(const int* __restrict__ esrc,
                                            const int* __restrict__ edst,
                                            int* __restrict__ fillp,
                                            int* __restrict__ srcs, int E)
{
  int e = blockIdx.x * 256 + threadIdx.x;
  if (e < E) {
    int d = edst[e];
    int p = atomicAdd(&fillp[d], 1);
    srcs[p] = esrc[e];
  }
}

// ---------------------------------------------------------------------------
// K3: fused node kernel (round-1 structure + LDS src window + 4-unroll):
//   out = relu( mean_{s in N(node)} x_src[s] @ W1 + x_own @ W2 + bias )
// Block = 64 nodes. Phase 0: stage block's CSR src indices into LDS (rare
// >SCAP overflow falls back to global). Phase 1: lane <-> (node m, 8-float
// k-slice); agg lanes run deg-loop 4-unrolled (8 independent 16B loads in
// flight), 16 lanes/node form a coalesced 512B row read; accumulate in regs,
// scale 1/deg, bf16-pack into MFMA A-frag layout in LDS. Phase 2: MFMA.
// mfma_f32_16x16x32_bf16 C/D: col=lane&15, row=(lane>>4)*4+reg   (m89/m91)
// ---------------------------------------------------------------------------
__global__ __launch_bounds__(256, 4) void fused_gemm(
    const float* __restrict__ xown, const float* __restrict__ xsrc,
    const int* __restrict__ rowp, const int* __restrict__ srcs,
    const unsigned short* __restrict__ Wp, const float* __restrict__ bias,
    float* __restrict__ outbase, int nvalid, int etotal)
{
  __shared__ __align__(16) uint4 ldsA4[2048];    // 32 KB packed A
  __shared__ int ldsS[SCAP];                     // 4 KB src-index window
  __shared__ int rb[65];                         // block row pointers
  int t = threadIdx.x;
  int node0 = blockIdx.x * 64;

  // ---- phase 0: row pointers + src-index window ----
  if (t < 65) {
    int node = node0 + t;
    rb[t] = node < nvalid ? rowp[node] : etotal;
  }
  __syncthreads();
  int rs0 = rb[0];
  int W = rb[64] - rs0;                          // block edge count
  for (int idx = t; idx < W && idx < SCAP; idx += 256)
    ldsS[idx] = srcs[rs0 + idx];
  __syncthreads();

  // ---- phase 1: gather+mean (agg half) / own row, bf16-pack to A-frag ----
  #pragma unroll
  for (int i = 0; i < 8; ++i) {
    int oid = t + i * 256;                       // 0..2047
    int m = oid >> 5;                            // node within block (0..63)
    int oct = oid & 31;                          // 8-float k-slice
    int node = node0 + m;
    float vals[8];
    #pragma unroll
    for (int j2 = 0; j2 < 8; ++j2) vals[j2] = 0.f;
    if (node < nvalid) {
      if (oct < 16) {                            // aggregation half, k0=oct*8
        int k0 = oct * 8;
        int erel = rb[m] - rs0;
        int deg = rb[m + 1] - rb[m];
        float a0=0,a1=0,a2=0,a3=0,a4=0,a5=0,a6=0,a7=0;
        int e = 0;
        for (; e + 4 <= deg; e += 4) {
          int q0 = erel + e;
          int s0 = (q0+0 < SCAP) ? ldsS[q0+0] : srcs[rs0+q0+0];
          int s1 = (q0+1 < SCAP) ? ldsS[q0+1] : srcs[rs0+q0+1];
          int s2 = (q0+2 < SCAP) ? ldsS[q0+2] : srcs[rs0+q0+2];
          int s3 = (q0+3 < SCAP) ? ldsS[q0+3] : srcs[rs0+q0+3];
          const float4* r0 = (const float4*)(xsrc + (size_t)s0 * 128 + k0);
          const float4* r1 = (const float4*)(xsrc + (size_t)s1 * 128 + k0);
          const float4* r2 = (const float4*)(xsrc + (size_t)s2 * 128 + k0);
          const float4* r3 = (const float4*)(xsrc + (size_t)s3 * 128 + k0);
          float4 l0 = r0[0], h0 = r0[1];
          float4 l1 = r1[0], h1 = r1[1];
          float4 l2 = r2[0], h2 = r2[1];
          float4 l3 = r3[0], h3 = r3[1];
          a0 += l0.x + l1.x + l2.x + l3.x;
          a1 += l0.y + l1.y + l2.y + l3.y;
          a2 += l0.z + l1.z + l2.z + l3.z;
          a3 += l0.w + l1.w + l2.w + l3.w;
          a4 += h0.x + h1.x + h2.x + h3.x;
          a5 += h0.y + h1.y + h2.y + h3.y;
          a6 += h0.z + h1.z + h2.z + h3.z;
          a7 += h0.w + h1.w + h2.w + h3.w;
        }
        for (; e < deg; ++e) {
          int q = erel + e;
          int s = (q < SCAP) ? ldsS[q] : srcs[rs0 + q];
          const float4* r = (const float4*)(xsrc + (size_t)s * 128 + k0);
          float4 l = r[0], h = r[1];
          a0 += l.x; a1 += l.y; a2 += l.z; a3 += l.w;
          a4 += h.x; a5 += h.y; a6 += h.z; a7 += h.w;
        }
        float sc = deg > 0 ? 1.0f / (float)deg : 0.f;
        vals[0]=a0*sc; vals[1]=a1*sc; vals[2]=a2*sc; vals[3]=a3*sc;
        vals[4]=a4*sc; vals[5]=a5*sc; vals[6]=a6*sc; vals[7]=a7*sc;
      } else {                                   // own-feature half
        int k0 = (oct - 16) * 8;
        const float4* p4 = (const float4*)(xown + (size_t)node * 128 + k0);
        float4 lo = p4[0], hi = p4[1];
        vals[0]=lo.x; vals[1]=lo.y; vals[2]=lo.z; vals[3]=lo.w;
        vals[4]=hi.x; vals[5]=hi.y; vals[6]=hi.z; vals[7]=hi.w;
      }
    }
    uint4 p;
    p.x = (unsigned)f2bf(vals[0]) | ((unsigned)f2bf(vals[1]) << 16);
    p.y = (unsigned)f2bf(vals[2]) | ((unsigned)f2bf(vals[3]) << 16);
    p.z = (unsigned)f2bf(vals[4]) | ((unsigned)f2bf(vals[5]) << 16);
    p.w = (unsigned)f2bf(vals[6]) | ((unsigned)f2bf(vals[7]) << 16);
    int ks = oct >> 2, quad = oct & 3;           // k_global = oct*8 (0..255)
    int mt = m >> 4, mlo = m & 15;
    ldsA4[(mt * 8 + ks) * 64 + quad * 16 + mlo] = p;
  }
  __syncthreads();

  // ---- phase 2: MFMA, wave = m-tile (16 nodes), 8 n-tiles, K=256 ----
  int wave = t >> 6, lane = t & 63;
  floatx4 acc[8];
  #pragma unroll
  for (int i = 0; i < 8; ++i) acc[i] = (floatx4){0.f, 0.f, 0.f, 0.f};
  const short8* A = (const short8*)ldsA4;
  const short8* B = (const short8*)Wp;
  #pragma unroll
  for (int kk = 0; kk < 8; ++kk) {
    short8 af = A[(wave * 8 + kk) * 64 + lane];
    #pragma unroll
    for (int nt = 0; nt < 8; ++nt) {
      short8 bf = B[(nt * 8 + kk) * 64 + lane];
      acc[nt] = __builtin_amdgcn_mfma_f32_16x16x32_bf16(af, bf, acc[nt], 0, 0, 0);
    }
  }

  // ---- epilogue: bias + relu ----
  int col = lane & 15, qrow = (lane >> 4) * 4;
  #pragma unroll
  for (int nt = 0; nt < 8; ++nt) {
    int n = nt * 16 + col;
    float bv = bias[n];
    #pragma unroll
    for (int r2 = 0; r2 < 4; ++r2) {
      int node = node0 + wave * 16 + qrow + r2;
      if (node < nvalid) {
        float v = acc[nt][r2] + bv;
        outbase[(size_t)node * 128 + n] = v > 0.f ? v : 0.f;
      }
    }
  }
}

// ---------------------------------------------------------------------------
// Workspace layout (bytes), total ~8.54 MB (cnt_* zeroed each call):
//   cnt_user @0 800000 | cnt_item @800000 400000 | row_user @1200000 800000
//   row_item @2000000 400000 | fill_user @2400000 800000 | fill_item @3200000 400000
//   srcs_user @3600000 2400000 | srcs_item @6000000 2400000
//   blks_user @8400000 1024 | blks_item @8401024 1024
//   boff_user @8402048 1024 | boff_item @8403072 1024
//   Wp_user @8404224 65536 | Wp_item @8469760 65536
//   bias_user @8535296 512 | bias_item @8535808 512
// ---------------------------------------------------------------------------
extern "C" void kernel_launch(void* const* d_in, const int* in_sizes, int n_in,
                              void* d_out, int out_size, void* d_ws, size_t ws_size,
                              hipStream_t stream)
{
  const float* x_user = (const float*)d_in[0];
  const float* x_item = (const float*)d_in[1];
  const int* esrc_ui  = (const int*)d_in[2];
  const int* edst_ui  = (const int*)d_in[3];
  const int* esrc_iu  = (const int*)d_in[4];
  const int* edst_iu  = (const int*)d_in[5];
  const float* Wl_ui  = (const float*)d_in[6];
  const float* bl_ui  = (const float*)d_in[7];
  const float* Wr_ui  = (const float*)d_in[8];
  const float* Wl_iu  = (const float*)d_in[9];
  const float* bl_iu  = (const float*)d_in[10];
  const float* Wr_iu  = (const float*)d_in[11];
  const float* W_user = (const float*)d_in[12];
  const float* b_user = (const float*)d_in[13];
  const float* W_item = (const float*)d_in[14];
  const float* b_item = (const float*)d_in[15];
  float* out = (float*)d_out;

  char* ws = (char*)d_ws;
  int* cnt_user  = (int*)(ws + 0);
  int* cnt_item  = (int*)(ws + 800000);
  int* row_user  = (int*)(ws + 1200000);
  int* row_item  = (int*)(ws + 2000000);
  int* fill_user = (int*)(ws + 2400000);
  int* fill_item = (int*)(ws + 3200000);
  int* srcs_user = (int*)(ws + 3600000);
  int* srcs_item = (int*)(ws + 6000000);
  int* blks_user = (int*)(ws + 8400000);
  int* blks_item = (int*)(ws + 8401024);
  int* boff_user = (int*)(ws + 8402048);
  int* boff_item = (int*)(ws + 8403072);
  unsigned short* Wp_user = (unsigned short*)(ws + 8404224);
  unsigned short* Wp_item = (unsigned short*)(ws + 8469760);
  float* bias_user = (float*)(ws + 8535296);
  float* bias_item = (float*)(ws + 8535808);

  // zero only the histograms (1.2 MB)
  hipMemsetAsync(d_ws, 0, 1200000, stream);

  fuse_weights<<<dim3(128, 4), 128, 0, stream>>>(Wl_iu, Wr_iu, Wl_ui, Wr_ui,
                                                 W_user, W_item, Wp_user, Wp_item);
  fuse_bias<<<2, 128, 0, stream>>>(bl_iu, b_user, W_user, bl_ui, b_item, W_item,
                                   bias_user, bias_item);

  const int EB = (EE + 255) / 256;            // 2344
  const int NBU = (NUu + 1023) / 1024;        // 196
  const int NBI = (NIi + 1023) / 1024;        // 98

  hist<<<EB, 256, 0, stream>>>(edst_iu, cnt_user, EE);
  hist<<<EB, 256, 0, stream>>>(edst_ui, cnt_item, EE);

  scan1<<<NBU, 256, 0, stream>>>(cnt_user, blks_user, NUu);
  scan1<<<NBI, 256, 0, stream>>>(cnt_item, blks_item, NIi);
  scan2<<<1, 256, 0, stream>>>(blks_user, boff_user, NBU);
  scan2<<<1, 256, 0, stream>>>(blks_item, boff_item, NBI);
  scan3<<<NBU, 256, 0, stream>>>(cnt_user, boff_user, row_user, fill_user, NUu);
  scan3<<<NBI, 256, 0, stream>>>(cnt_item, boff_item, row_item, fill_item, NIi);

  fill<<<EB, 256, 0, stream>>>(esrc_iu, edst_iu, fill_user, srcs_user, EE);
  fill<<<EB, 256, 0, stream>>>(esrc_ui, edst_ui, fill_item, srcs_item, EE);

  fused_gemm<<<(NUu + 63) / 64, 256, 0, stream>>>(x_user, x_item, row_user,
                                                  srcs_user, Wp_user, bias_user,
                                                  out, NUu, EE);
  fused_gemm<<<(NIi + 63) / 64, 256, 0, stream>>>(x_item, x_user, row_item,
                                                  srcs_item, Wp_item, bias_item,
                                                  out + (size_t)NUu * 128, NIi, EE);
}